// Round 12
// baseline (300.842 us; speedup 1.0000x reference)
//
#include <hip/hip_runtime.h>
#include <stdint.h>

// Actor_attf_single — MI355X (gfx950)
// R21: R20 + ALL remaining weights/biases -> LDS. Ledger:
//   R19 173.5us (input prefetch; stall 81K)
//   R20 160us   (oa/go pass weights via LDS; busy 301K, stall 83K, VGPR 84)
// Remaining SMEM streams with lgkmcnt(0) drains: head a_W1/W2/W3 (1312 u32
// per role-0 wave, drains threaded through 40 cp iterations) and self
// encoder (320 u32, paid by BOTH roles). R21 mirrors the whole packed pool
// (2240 u32) + fp32 biases/LN (258 fl) into LDS once per block (~10KB;
// +fpool = 18.7KB). Same bits, same order -> BITWISE-IDENTICAL math.
// Codegen rules (R10/R20 lessons): uint4/uint2 LDS reads consumed
// immediately; unroll 2 on jp loops; head cp loops FULLY unrolled (mh
// indexing must stay static - runtime-indexed reg arrays go to scratch).
// Tripwires: VGPR > 128 or WRITE_SIZE > 6MB => revert to R20.

#define LN_EPS 1e-5f

typedef _Float16 h2 __attribute__((ext_vector_type(2)));

struct Weights {
  const float* __restrict__ en_W1; const float* __restrict__ en_b1;
  const float* __restrict__ en_W2; const float* __restrict__ en_b2;
  const float* __restrict__ oa_W1; const float* __restrict__ oa_b1;
  const float* __restrict__ oa_W2; const float* __restrict__ oa_b2;
  const float* __restrict__ go_W1; const float* __restrict__ go_b1;
  const float* __restrict__ go_W2; const float* __restrict__ go_b2;
  const float* __restrict__ oa_g;  const float* __restrict__ oa_b;
  const float* __restrict__ go_g;  const float* __restrict__ go_b;
  const float* __restrict__ a_W1;  const float* __restrict__ a_b1;
  const float* __restrict__ a_W2;  const float* __restrict__ a_b2;
  const float* __restrict__ a_W3;  const float* __restrict__ a_b3;
};

// packed-weight layout (u32) — identical in workspace and LDS mirror
constexpr int P_EN_W1 = 0;     //  64: [j]=rows(0,1), [32+j]=rows(2,3)
constexpr int P_EN_W2 = 64;    // 256: [jp*16+d]
constexpr int P_OA_W1 = 320;   //  64
constexpr int P_OA_W2 = 384;   // 256
constexpr int P_GO_W1 = 640;   //  32
constexpr int P_GO_W2 = 672;   // 256
constexpr int P_A_W1  = 928;   // 768: [cp*32+j]
constexpr int P_A_W2  = 1696;  // 512
constexpr int P_A_W3  = 2208;  //  32
constexpr int P_TOTAL = 2240;  // 8960 bytes

// fp32 bias/LN region (float offsets, after P_TOTAL u32 slots)
constexpr int B_EN1 = 0;    // 32
constexpr int B_EN2 = 32;   // 16
constexpr int B_OA1 = 48;   // 32
constexpr int B_OA2 = 80;   // 16
constexpr int B_GO1 = 96;   // 32
constexpr int B_GO2 = 112;  // 16
constexpr int B_OAG = 128;  // 16
constexpr int B_OAB = 144;  // 16
constexpr int B_GOG = 160;  // 16
constexpr int B_GOB = 176;  // 16
constexpr int B_A1  = 192;  // 32
constexpr int B_A2  = 224;  // 32
constexpr int B_A3  = 256;  // 2
constexpr int B_TOTAL = 258;

__device__ __forceinline__ float2 ld2(const float* __restrict__ p) {
  return *reinterpret_cast<const float2*>(p);
}
__device__ __forceinline__ float4 ld4(const float* __restrict__ p) {
  return *reinterpret_cast<const float4*>(p);
}
__device__ __forceinline__ uint32_t pack_rne(float a, float b) {
  h2 v; v.x = (_Float16)a; v.y = (_Float16)b;
  return __builtin_bit_cast(uint32_t, v);
}
__device__ __forceinline__ h2 asH2(uint32_t u) { return __builtin_bit_cast(h2, u); }
__device__ __forceinline__ float fdot2(h2 a, h2 b, float c) {
  return __builtin_amdgcn_fdot2(a, b, c, false);
}
__device__ __forceinline__ h2 pkrtz(float a, float b) {
  return __builtin_bit_cast(h2, __builtin_amdgcn_cvt_pkrtz(a, b));
}

// ---- prep: fp32 weights -> packed half2 in workspace (unchanged) ---------
__global__ void prep_weights(Weights W, uint32_t* __restrict__ ws) {
  const int t = threadIdx.x;
  if (t < 32) {
    ws[P_EN_W1 + t]      = pack_rne(W.en_W1[t],      W.en_W1[32 + t]);
    ws[P_EN_W1 + 32 + t] = pack_rne(W.en_W1[64 + t], W.en_W1[96 + t]);
    ws[P_OA_W1 + t]      = pack_rne(W.oa_W1[t],      W.oa_W1[32 + t]);
    ws[P_OA_W1 + 32 + t] = pack_rne(W.oa_W1[64 + t], W.oa_W1[96 + t]);
    ws[P_GO_W1 + t]      = pack_rne(W.go_W1[t],      W.go_W1[32 + t]);
  }
  {
    int jp = t >> 4, d = t & 15;
    ws[P_EN_W2 + t] = pack_rne(W.en_W2[(2*jp)*16 + d], W.en_W2[(2*jp+1)*16 + d]);
    ws[P_OA_W2 + t] = pack_rne(W.oa_W2[(2*jp)*16 + d], W.oa_W2[(2*jp+1)*16 + d]);
    ws[P_GO_W2 + t] = pack_rne(W.go_W2[(2*jp)*16 + d], W.go_W2[(2*jp+1)*16 + d]);
  }
  for (int i = t; i < 768; i += 256) {
    int cp = i >> 5, j = i & 31;
    ws[P_A_W1 + i] = pack_rne(W.a_W1[(2*cp)*32 + j], W.a_W1[(2*cp+1)*32 + j]);
  }
  for (int i = t; i < 512; i += 256) {
    int cp = i >> 5, j = i & 31;
    ws[P_A_W2 + i] = pack_rne(W.a_W2[(2*cp)*32 + j], W.a_W2[(2*cp+1)*32 + j]);
  }
  if (t < 32) {
    int cp = t >> 1, o = t & 1;
    ws[P_A_W3 + t] = pack_rne(W.a_W3[(2*cp)*2 + o], W.a_W3[(2*cp+1)*2 + o]);
  }
}

// ---- one batch of 3 "other" entities (inputs pre-loaded, weights LDS) ----
__device__ __forceinline__ void oa_batch3(const float2 (&i01)[3],
                                          const float2 (&i23)[3],
                                          const uint32_t* __restrict__ swl,
                                          const float* __restrict__ swf,
                                          const float (&self_out)[16],
                                          float (&acc)[16], float& m, float& l) {
  h2 a01[3], a23[3];
#pragma unroll
  for (int e = 0; e < 3; ++e) {
    a01[e] = pkrtz(i01[e].x, i01[e].y);
    a23[e] = pkrtz(i23[e].x, i23[e].y);
  }
  float enc[3][16];
#pragma unroll
  for (int d = 0; d < 16; ++d) {
    float b2 = swf[B_OA2 + d];
#pragma unroll
    for (int e = 0; e < 3; ++e) enc[e][d] = b2;
  }
#pragma unroll 2
  for (int jp = 0; jp < 16; ++jp) {
    const uint2 wa = *reinterpret_cast<const uint2*>(&swl[P_OA_W1 + 2*jp]);
    const uint2 wb = *reinterpret_cast<const uint2*>(&swl[P_OA_W1 + 32 + 2*jp]);
    const float2 bb = *reinterpret_cast<const float2*>(&swf[B_OA1 + 2*jp]);
    const uint4 q0 = *reinterpret_cast<const uint4*>(&swl[P_OA_W2 + jp*16 + 0]);
    const uint4 q1 = *reinterpret_cast<const uint4*>(&swl[P_OA_W2 + jp*16 + 4]);
    const uint4 q2 = *reinterpret_cast<const uint4*>(&swl[P_OA_W2 + jp*16 + 8]);
    const uint4 q3 = *reinterpret_cast<const uint4*>(&swl[P_OA_W2 + jp*16 + 12]);
    const h2 wA0 = asH2(wa.x), wA1 = asH2(wa.y);
    const h2 wB0 = asH2(wb.x), wB1 = asH2(wb.y);
    h2 hh[3];
#pragma unroll
    for (int e = 0; e < 3; ++e) {
      float h0 = fmaxf(fdot2(a01[e], wA0, fdot2(a23[e], wB0, bb.x)), 0.f);
      float h1 = fmaxf(fdot2(a01[e], wA1, fdot2(a23[e], wB1, bb.y)), 0.f);
      hh[e] = pkrtz(h0, h1);
    }
    const uint32_t l2[16] = {q0.x, q0.y, q0.z, q0.w, q1.x, q1.y, q1.z, q1.w,
                             q2.x, q2.y, q2.z, q2.w, q3.x, q3.y, q3.z, q3.w};
#pragma unroll
    for (int d = 0; d < 16; ++d) {
      const h2 wd = asH2(l2[d]);
#pragma unroll
      for (int e = 0; e < 3; ++e) enc[e][d] = fdot2(hh[e], wd, enc[e][d]);
    }
  }
  // per-entity epilogue, strictly in entity order (fp32, verbatim R20)
#pragma unroll
  for (int e = 0; e < 3; ++e) {
    float s = 0.f;
#pragma unroll
    for (int d = 0; d < 16; ++d) {
      enc[e][d] = fmaxf(enc[e][d], 0.f);
      s = fmaf(self_out[d], enc[e][d], s);
    }
    s *= 0.25f;
    float mn = fmaxf(m, s);
    float alpha = __expf(m - mn), w = __expf(s - mn);
    l = fmaf(l, alpha, w);
#pragma unroll
    for (int d = 0; d < 16; ++d) acc[d] = fmaf(acc[d], alpha, w * enc[e][d]);
    m = mn;
  }
}

// ---- one batch of 4 "food" entities (inputs pre-loaded, weights LDS) -----
__device__ __forceinline__ void go_batch4(const float4 q0i, const float4 q1i,
                                          const uint32_t* __restrict__ swl,
                                          const float* __restrict__ swf,
                                          const float (&self_out)[16],
                                          float (&acc)[16], float& m, float& l) {
  h2 ah[4];
  ah[0] = pkrtz(q0i.x, q0i.y);
  ah[1] = pkrtz(q0i.z, q0i.w);
  ah[2] = pkrtz(q1i.x, q1i.y);
  ah[3] = pkrtz(q1i.z, q1i.w);
  float enc[4][16];
#pragma unroll
  for (int d = 0; d < 16; ++d) {
    float b2 = swf[B_GO2 + d];
#pragma unroll
    for (int e = 0; e < 4; ++e) enc[e][d] = b2;
  }
#pragma unroll 2
  for (int jp = 0; jp < 16; ++jp) {
    const uint2 g1 = *reinterpret_cast<const uint2*>(&swl[P_GO_W1 + 2*jp]);
    const float2 bb = *reinterpret_cast<const float2*>(&swf[B_GO1 + 2*jp]);
    const uint4 q0 = *reinterpret_cast<const uint4*>(&swl[P_GO_W2 + jp*16 + 0]);
    const uint4 q1 = *reinterpret_cast<const uint4*>(&swl[P_GO_W2 + jp*16 + 4]);
    const uint4 q2 = *reinterpret_cast<const uint4*>(&swl[P_GO_W2 + jp*16 + 8]);
    const uint4 q3 = *reinterpret_cast<const uint4*>(&swl[P_GO_W2 + jp*16 + 12]);
    const h2 w0 = asH2(g1.x), w1 = asH2(g1.y);
    h2 hh[4];
#pragma unroll
    for (int e = 0; e < 4; ++e) {
      float h0 = fmaxf(fdot2(ah[e], w0, bb.x), 0.f);
      float h1 = fmaxf(fdot2(ah[e], w1, bb.y), 0.f);
      hh[e] = pkrtz(h0, h1);
    }
    const uint32_t l2[16] = {q0.x, q0.y, q0.z, q0.w, q1.x, q1.y, q1.z, q1.w,
                             q2.x, q2.y, q2.z, q2.w, q3.x, q3.y, q3.z, q3.w};
#pragma unroll
    for (int d = 0; d < 16; ++d) {
      const h2 wd = asH2(l2[d]);
#pragma unroll
      for (int e = 0; e < 4; ++e) enc[e][d] = fdot2(hh[e], wd, enc[e][d]);
    }
  }
  // per-entity epilogue, strictly in entity order (fp32, verbatim R20)
#pragma unroll
  for (int e = 0; e < 4; ++e) {
    float s = 0.f;
#pragma unroll
    for (int d = 0; d < 16; ++d) {
      enc[e][d] = fmaxf(enc[e][d], 0.f);
      s = fmaf(self_out[d], enc[e][d], s);
    }
    s *= 0.25f;
    float mn = fmaxf(m, s);
    float alpha = __expf(m - mn), w = __expf(s - mn);
    l = fmaf(l, alpha, w);
#pragma unroll
    for (int d = 0; d < 16; ++d) acc[d] = fmaf(acc[d], alpha, w * enc[e][d]);
    m = mn;
  }
}

__global__ __launch_bounds__(256, 2)
void actor_fwd(const float* __restrict__ s_input, Weights W,
               const uint32_t* __restrict__ wsu,
               float* __restrict__ out, int bsz) {
  const int lane    = threadIdx.x & 63;
  const int wv      = threadIdx.x >> 6;      // 0..3
  const int pairIdx = wv >> 1;               // 0..1  (64-row group)
  const int role    = wv & 1;                // 0: other+head, 1: food
  int row = blockIdx.x * 128 + pairIdx * 64 + lane;
  row = min(row, bsz - 1);
  const float* __restrict__ srow = s_input + (size_t)row * 96;

  __shared__ __align__(16) uint32_t swl[P_TOTAL + B_TOTAL];  // ~10.0KB
  __shared__ float fpool[2][64][17];                         // +1 pad

  // ---- one-time staging: full packed mirror + fp32 biases ---------------
  {
    const int t = threadIdx.x;
    float* swf_ = reinterpret_cast<float*>(swl + P_TOTAL);
#pragma unroll 1
    for (int i = t; i < P_TOTAL; i += 256) swl[i] = wsu[i];
    if (t < 32) {
      swf_[B_EN1 + t] = W.en_b1[t];
      swf_[B_OA1 + t] = W.oa_b1[t];
      swf_[B_GO1 + t] = W.go_b1[t];
      swf_[B_A1  + t] = W.a_b1[t];
      swf_[B_A2  + t] = W.a_b2[t];
    }
    if (t < 16) {
      swf_[B_EN2 + t] = W.en_b2[t];
      swf_[B_OA2 + t] = W.oa_b2[t];
      swf_[B_GO2 + t] = W.go_b2[t];
      swf_[B_OAG + t] = W.oa_g[t];
      swf_[B_OAB + t] = W.oa_b[t];
      swf_[B_GOG + t] = W.go_g[t];
      swf_[B_GOB + t] = W.go_b[t];
    }
    if (t < 2) swf_[B_A3 + t] = W.a_b3[t];
  }

  // ---- prefetch: self inputs (both) + batch-0 inputs (per role) ---------
  float4 pself = ld4(srow);                  // cols 0..3, 16B-aligned
  float2 pre01[3], pre23[3];                 // oa pipeline regs (role 0)
  float4 preq0, preq1;                       // go pipeline regs (role 1)
  if (role == 0) {
#pragma unroll
    for (int e = 0; e < 3; ++e) {
      pre01[e] = ld2(srow + 4  + 2*e);
      pre23[e] = ld2(srow + 34 + 2*e);
    }
  } else {
    preq0 = ld4(srow + 64);                  // cols 64..67, aligned
    preq1 = ld4(srow + 68);
  }

  __syncthreads();                           // staging visible to all waves
  const float* __restrict__ swf = reinterpret_cast<const float*>(swl + P_TOTAL);

  // ---------------- self encoder (both roles): 4 -> 32 -> 16, relu --------
  float self_out[16];
  {
    h2 a01 = pkrtz(pself.x, pself.y);
    h2 a23 = pkrtz(pself.z, pself.w);
#pragma unroll
    for (int d = 0; d < 16; ++d) self_out[d] = swf[B_EN2 + d];
#pragma unroll 2
    for (int jp = 0; jp < 16; ++jp) {
      const uint2 ea = *reinterpret_cast<const uint2*>(&swl[P_EN_W1 + 2*jp]);
      const uint2 eb = *reinterpret_cast<const uint2*>(&swl[P_EN_W1 + 32 + 2*jp]);
      const float2 ebias = *reinterpret_cast<const float2*>(&swf[B_EN1 + 2*jp]);
      float h0 = fmaxf(fdot2(a01, asH2(ea.x), fdot2(a23, asH2(eb.x), ebias.x)), 0.f);
      float h1 = fmaxf(fdot2(a01, asH2(ea.y), fdot2(a23, asH2(eb.y), ebias.y)), 0.f);
      h2 hh = pkrtz(h0, h1);
      const uint4 q0 = *reinterpret_cast<const uint4*>(&swl[P_EN_W2 + jp*16 + 0]);
      const uint4 q1 = *reinterpret_cast<const uint4*>(&swl[P_EN_W2 + jp*16 + 4]);
      const uint4 q2 = *reinterpret_cast<const uint4*>(&swl[P_EN_W2 + jp*16 + 8]);
      const uint4 q3 = *reinterpret_cast<const uint4*>(&swl[P_EN_W2 + jp*16 + 12]);
      const uint32_t l2[16] = {q0.x, q0.y, q0.z, q0.w, q1.x, q1.y, q1.z, q1.w,
                               q2.x, q2.y, q2.z, q2.w, q3.x, q3.y, q3.z, q3.w};
#pragma unroll
      for (int d = 0; d < 16; ++d)
        self_out[d] = fdot2(hh, asH2(l2[d]), self_out[d]);
    }
#pragma unroll
    for (int d = 0; d < 16; ++d) self_out[d] = fmaxf(self_out[d], 0.f);
  }

  float other_pool[16];

  if (role == 0) {
    // ------- other agents: 15 entities = 5 passes of 3, prefetched -------
    float m = -3.0e38f, l = 0.f, acc[16];
#pragma unroll
    for (int d = 0; d < 16; ++d) acc[d] = 0.f;
#pragma unroll 1
    for (int k0 = 0; k0 < 15; k0 += 3) {
      float2 c01[3], c23[3];
#pragma unroll
      for (int e = 0; e < 3; ++e) { c01[e] = pre01[e]; c23[e] = pre23[e]; }
      if (k0 + 3 < 15) {
#pragma unroll
        for (int e = 0; e < 3; ++e) {
          pre01[e] = ld2(srow + 4  + 2*(k0 + 3 + e));
          pre23[e] = ld2(srow + 34 + 2*(k0 + 3 + e));
        }
      }
      oa_batch3(c01, c23, swl, swf, self_out, acc, m, l);
    }

    float inv = 1.f / l;
    float mu = 0.f;
#pragma unroll
    for (int d = 0; d < 16; ++d) { acc[d] *= inv; mu += acc[d]; }
    mu *= (1.f / 16.f);
    float var = 0.f;
#pragma unroll
    for (int d = 0; d < 16; ++d) { float x = acc[d] - mu; var = fmaf(x, x, var); }
    var *= (1.f / 16.f);
    float rstd = rsqrtf(var + LN_EPS);
#pragma unroll
    for (int d = 0; d < 16; ++d)
      other_pool[d] = fmaxf(fmaf((acc[d] - mu) * rstd, swf[B_OAG + d], swf[B_OAB + d]), 0.f);
  } else {
    // ------- food: 16 entities = 4 passes of 4 (float4), prefetched ------
    float m = -3.0e38f, l = 0.f, acc[16];
#pragma unroll
    for (int d = 0; d < 16; ++d) acc[d] = 0.f;
#pragma unroll 1
    for (int k0 = 0; k0 < 16; k0 += 4) {
      float4 c0 = preq0, c1 = preq1;
      if (k0 + 4 < 16) {
        preq0 = ld4(srow + 64 + 2*(k0 + 4));
        preq1 = ld4(srow + 68 + 2*(k0 + 4));
      }
      go_batch4(c0, c1, swl, swf, self_out, acc, m, l);
    }

    float inv = 1.f / l;
    float mu = 0.f;
#pragma unroll
    for (int d = 0; d < 16; ++d) { acc[d] *= inv; mu += acc[d]; }
    mu *= (1.f / 16.f);
    float var = 0.f;
#pragma unroll
    for (int d = 0; d < 16; ++d) { float x = acc[d] - mu; var = fmaf(x, x, var); }
    var *= (1.f / 16.f);
    float rstd = rsqrtf(var + LN_EPS);
#pragma unroll
    for (int d = 0; d < 16; ++d) {
      float fp = fmaxf(fmaf((acc[d] - mu) * rstd, swf[B_GOG + d], swf[B_GOB + d]), 0.f);
      fpool[pairIdx][lane][d] = fp;
    }
  }

  __syncthreads();
  if (role != 0) return;

  // ------- action head (role 0): 48 -> 32 -> 32 -> 2, weights via LDS ----
  float food_pool[16];
#pragma unroll
  for (int d = 0; d < 16; ++d) food_pool[d] = fpool[pairIdx][lane][d];

  h2 mh[24];
#pragma unroll
  for (int c = 0; c < 8; ++c) mh[c]      = pkrtz(self_out[2*c],  self_out[2*c+1]);
#pragma unroll
  for (int c = 0; c < 8; ++c) mh[8 + c]  = pkrtz(food_pool[2*c], food_pool[2*c+1]);
#pragma unroll
  for (int c = 0; c < 8; ++c) mh[16 + c] = pkrtz(other_pool[2*c], other_pool[2*c+1]);

  float h1v[32];
#pragma unroll
  for (int j = 0; j < 32; ++j) h1v[j] = swf[B_A1 + j];
#pragma unroll
  for (int cp = 0; cp < 24; ++cp) {      // full unroll: mh index must be static
    h2 v = mh[cp];
#pragma unroll
    for (int g = 0; g < 8; ++g) {        // uint4 consumed immediately
      const uint4 q = *reinterpret_cast<const uint4*>(&swl[P_A_W1 + cp*32 + g*4]);
      h1v[4*g+0] = fdot2(v, asH2(q.x), h1v[4*g+0]);
      h1v[4*g+1] = fdot2(v, asH2(q.y), h1v[4*g+1]);
      h1v[4*g+2] = fdot2(v, asH2(q.z), h1v[4*g+2]);
      h1v[4*g+3] = fdot2(v, asH2(q.w), h1v[4*g+3]);
    }
  }
#pragma unroll
  for (int j = 0; j < 32; ++j) h1v[j] = fmaxf(h1v[j], 0.01f * h1v[j]);  // leaky

  h2 hh1[16];
#pragma unroll
  for (int c = 0; c < 16; ++c) hh1[c] = pkrtz(h1v[2*c], h1v[2*c+1]);

  float h2v[32];
#pragma unroll
  for (int j = 0; j < 32; ++j) h2v[j] = swf[B_A2 + j];
#pragma unroll
  for (int cp = 0; cp < 16; ++cp) {      // full unroll: hh1 index static
    h2 v = hh1[cp];
#pragma unroll
    for (int g = 0; g < 8; ++g) {
      const uint4 q = *reinterpret_cast<const uint4*>(&swl[P_A_W2 + cp*32 + g*4]);
      h2v[4*g+0] = fdot2(v, asH2(q.x), h2v[4*g+0]);
      h2v[4*g+1] = fdot2(v, asH2(q.y), h2v[4*g+1]);
      h2v[4*g+2] = fdot2(v, asH2(q.z), h2v[4*g+2]);
      h2v[4*g+3] = fdot2(v, asH2(q.w), h2v[4*g+3]);
    }
  }
#pragma unroll
  for (int j = 0; j < 32; ++j) h2v[j] = fmaxf(h2v[j], 0.01f * h2v[j]);

  h2 hh2[16];
#pragma unroll
  for (int c = 0; c < 16; ++c) hh2[c] = pkrtz(h2v[2*c], h2v[2*c+1]);

  float o0 = swf[B_A3 + 0], o1 = swf[B_A3 + 1];
#pragma unroll
  for (int cp = 0; cp < 16; ++cp) {
    const uint2 q = *reinterpret_cast<const uint2*>(&swl[P_A_W3 + cp*2]);
    o0 = fdot2(hh2[cp], asH2(q.x), o0);
    o1 = fdot2(hh2[cp], asH2(q.y), o1);
  }
  o0 = tanhf(o0);
  o1 = tanhf(o1);

  reinterpret_cast<float2*>(out)[row] = make_float2(o0, o1);
}

extern "C" void kernel_launch(void* const* d_in, const int* in_sizes, int n_in,
                              void* d_out, int out_size, void* d_ws, size_t ws_size,
                              hipStream_t stream) {
  const float* s_input = (const float*)d_in[0];
  Weights W;
  W.en_W1 = (const float*)d_in[1];  W.en_b1 = (const float*)d_in[2];
  W.en_W2 = (const float*)d_in[3];  W.en_b2 = (const float*)d_in[4];
  W.oa_W1 = (const float*)d_in[5];  W.oa_b1 = (const float*)d_in[6];
  W.oa_W2 = (const float*)d_in[7];  W.oa_b2 = (const float*)d_in[8];
  W.go_W1 = (const float*)d_in[9];  W.go_b1 = (const float*)d_in[10];
  W.go_W2 = (const float*)d_in[11]; W.go_b2 = (const float*)d_in[12];
  W.oa_g  = (const float*)d_in[13]; W.oa_b  = (const float*)d_in[14];
  W.go_g  = (const float*)d_in[15]; W.go_b  = (const float*)d_in[16];
  W.a_W1  = (const float*)d_in[17]; W.a_b1  = (const float*)d_in[18];
  W.a_W2  = (const float*)d_in[19]; W.a_b2  = (const float*)d_in[20];
  W.a_W3  = (const float*)d_in[21]; W.a_b3  = (const float*)d_in[22];

  uint32_t* wsu = (uint32_t*)d_ws;   // needs 8960 bytes
  prep_weights<<<1, 256, 0, stream>>>(W, wsu);

  const int bsz = in_sizes[0] / 96;          // 262144
  const int blocks = (bsz + 127) / 128;      // 128 rows/block: 2 groups x 2 roles
  actor_fwd<<<blocks, 256, 0, stream>>>(s_input, W, wsu, (float*)d_out, bsz);
}

// Round 13
// 297.484 us; speedup vs baseline: 1.0113x; 1.0113x over previous
//
#include <hip/hip_runtime.h>
#include <stdint.h>

// Actor_attf_single — MI355X (gfx950)
// R22: R20 (best: 160us) + ONE change: head weights (a_W1/W2/W3, 1312 u32)
// via LDS. Ledger:
//   R20 160us: oa/go pass weights via LDS (busy 301K, stall 83K, VGPR 84)
//   R21 166us: EVERYTHING via LDS -> stall 83->97K. Bundled 3 moves; the
//       self-encoder move is the suspect (runs right after staging barrier
//       in BOTH roles, ds_reads with nothing to overlap; SMEM self stream
//       was scalar-pipe + amortized). Head move was masked.
// R22 isolates the head move: 1312 u32 threaded through 40 cp iterations
// of lgkmcnt(0) drains on the role-0 critical path. Self + all biases stay
// SMEM exactly as R20. Math BITWISE-IDENTICAL. absmax must stay 0.00390625.
// Pre-commit: >=160us => revert to R20 verbatim, declare plateau.
// Tripwires: VGPR > 128 or WRITE_SIZE > 6MB => revert.

#define LN_EPS 1e-5f

typedef _Float16 h2 __attribute__((ext_vector_type(2)));

struct Weights {
  const float* __restrict__ en_W1; const float* __restrict__ en_b1;
  const float* __restrict__ en_W2; const float* __restrict__ en_b2;
  const float* __restrict__ oa_W1; const float* __restrict__ oa_b1;
  const float* __restrict__ oa_W2; const float* __restrict__ oa_b2;
  const float* __restrict__ go_W1; const float* __restrict__ go_b1;
  const float* __restrict__ go_W2; const float* __restrict__ go_b2;
  const float* __restrict__ oa_g;  const float* __restrict__ oa_b;
  const float* __restrict__ go_g;  const float* __restrict__ go_b;
  const float* __restrict__ a_W1;  const float* __restrict__ a_b1;
  const float* __restrict__ a_W2;  const float* __restrict__ a_b2;
  const float* __restrict__ a_W3;  const float* __restrict__ a_b3;
};

// workspace layout (uint32 = packed half2 units)
constexpr int P_EN_W1 = 0;     //  64
constexpr int P_EN_W2 = 64;    // 256
constexpr int P_OA_W1 = 320;   //  64
constexpr int P_OA_W2 = 384;   // 256
constexpr int P_GO_W1 = 640;   //  32
constexpr int P_GO_W2 = 672;   // 256
constexpr int P_A_W1  = 928;   // 768: [cp*32+j]
constexpr int P_A_W2  = 1696;  // 512
constexpr int P_A_W3  = 2208;  //  32
// total 2240 u32 = 8960 bytes

// LDS weight-pool offsets (u32 units; uint4 arrays 16B-aligned)
constexpr int L_OA_L1 = 0;     //  64: [jp*4+c] = {wA0,wA1,wB0,wB1}
constexpr int L_OA_L2 = 64;    // 256: [jp*16+d]
constexpr int L_GO_L2 = 320;   // 256: [jp*16+d]
constexpr int L_GO_L1 = 576;   //  32: [jp*2+{0,1}]
constexpr int L_OA_B1 = 608;   //  32 floats
constexpr int L_GO_B1 = 640;   //  32 floats
constexpr int H_A_W1  = 672;   // 768   (byte 2688, 16B-aligned)
constexpr int H_A_W2  = 1440;  // 512   (byte 5760, 16B-aligned)
constexpr int H_A_W3  = 1952;  //  32   (byte 7808, 8B-aligned)
constexpr int L_TOTAL = 1984;  // 7936 bytes

__device__ __forceinline__ float2 ld2(const float* __restrict__ p) {
  return *reinterpret_cast<const float2*>(p);
}
__device__ __forceinline__ float4 ld4(const float* __restrict__ p) {
  return *reinterpret_cast<const float4*>(p);
}
__device__ __forceinline__ uint32_t pack_rne(float a, float b) {
  h2 v; v.x = (_Float16)a; v.y = (_Float16)b;
  return __builtin_bit_cast(uint32_t, v);
}
__device__ __forceinline__ h2 asH2(uint32_t u) { return __builtin_bit_cast(h2, u); }
__device__ __forceinline__ float fdot2(h2 a, h2 b, float c) {
  return __builtin_amdgcn_fdot2(a, b, c, false);
}
__device__ __forceinline__ h2 pkrtz(float a, float b) {
  return __builtin_bit_cast(h2, __builtin_amdgcn_cvt_pkrtz(a, b));
}

// ---- prep: fp32 weights -> packed half2 in workspace ---------------------
__global__ void prep_weights(Weights W, uint32_t* __restrict__ ws) {
  const int t = threadIdx.x;
  if (t < 32) {
    ws[P_EN_W1 + t]      = pack_rne(W.en_W1[t],      W.en_W1[32 + t]);
    ws[P_EN_W1 + 32 + t] = pack_rne(W.en_W1[64 + t], W.en_W1[96 + t]);
    ws[P_OA_W1 + t]      = pack_rne(W.oa_W1[t],      W.oa_W1[32 + t]);
    ws[P_OA_W1 + 32 + t] = pack_rne(W.oa_W1[64 + t], W.oa_W1[96 + t]);
    ws[P_GO_W1 + t]      = pack_rne(W.go_W1[t],      W.go_W1[32 + t]);
  }
  {
    int jp = t >> 4, d = t & 15;
    ws[P_EN_W2 + t] = pack_rne(W.en_W2[(2*jp)*16 + d], W.en_W2[(2*jp+1)*16 + d]);
    ws[P_OA_W2 + t] = pack_rne(W.oa_W2[(2*jp)*16 + d], W.oa_W2[(2*jp+1)*16 + d]);
    ws[P_GO_W2 + t] = pack_rne(W.go_W2[(2*jp)*16 + d], W.go_W2[(2*jp+1)*16 + d]);
  }
  for (int i = t; i < 768; i += 256) {
    int cp = i >> 5, j = i & 31;
    ws[P_A_W1 + i] = pack_rne(W.a_W1[(2*cp)*32 + j], W.a_W1[(2*cp+1)*32 + j]);
  }
  for (int i = t; i < 512; i += 256) {
    int cp = i >> 5, j = i & 31;
    ws[P_A_W2 + i] = pack_rne(W.a_W2[(2*cp)*32 + j], W.a_W2[(2*cp+1)*32 + j]);
  }
  if (t < 32) {
    int cp = t >> 1, o = t & 1;
    ws[P_A_W3 + t] = pack_rne(W.a_W3[(2*cp)*2 + o], W.a_W3[(2*cp+1)*2 + o]);
  }
}

// ---- one batch of 3 "other" entities (inputs pre-loaded, weights LDS) ----
__device__ __forceinline__ void oa_batch3(const float2 (&i01)[3],
                                          const float2 (&i23)[3],
                                          const Weights& W,
                                          const uint32_t* __restrict__ swl,
                                          const float (&self_out)[16],
                                          float (&acc)[16], float& m, float& l) {
  h2 a01[3], a23[3];
#pragma unroll
  for (int e = 0; e < 3; ++e) {
    a01[e] = pkrtz(i01[e].x, i01[e].y);
    a23[e] = pkrtz(i23[e].x, i23[e].y);
  }
  float enc[3][16];
#pragma unroll
  for (int d = 0; d < 16; ++d) {
    float b2 = W.oa_b2[d];
#pragma unroll
    for (int e = 0; e < 3; ++e) enc[e][d] = b2;
  }
#pragma unroll 2
  for (int jp = 0; jp < 16; ++jp) {
    const uint4 l1 = *reinterpret_cast<const uint4*>(&swl[L_OA_L1 + jp*4]);
    const float2 bb = *reinterpret_cast<const float2*>(
        &reinterpret_cast<const float*>(swl)[L_OA_B1 + jp*2]);
    const uint4 q0 = *reinterpret_cast<const uint4*>(&swl[L_OA_L2 + jp*16 + 0]);
    const uint4 q1 = *reinterpret_cast<const uint4*>(&swl[L_OA_L2 + jp*16 + 4]);
    const uint4 q2 = *reinterpret_cast<const uint4*>(&swl[L_OA_L2 + jp*16 + 8]);
    const uint4 q3 = *reinterpret_cast<const uint4*>(&swl[L_OA_L2 + jp*16 + 12]);
    const h2 wA0 = asH2(l1.x), wA1 = asH2(l1.y);
    const h2 wB0 = asH2(l1.z), wB1 = asH2(l1.w);
    h2 hh[3];
#pragma unroll
    for (int e = 0; e < 3; ++e) {
      float h0 = fmaxf(fdot2(a01[e], wA0, fdot2(a23[e], wB0, bb.x)), 0.f);
      float h1 = fmaxf(fdot2(a01[e], wA1, fdot2(a23[e], wB1, bb.y)), 0.f);
      hh[e] = pkrtz(h0, h1);
    }
    const uint32_t l2[16] = {q0.x, q0.y, q0.z, q0.w, q1.x, q1.y, q1.z, q1.w,
                             q2.x, q2.y, q2.z, q2.w, q3.x, q3.y, q3.z, q3.w};
#pragma unroll
    for (int d = 0; d < 16; ++d) {
      const h2 wd = asH2(l2[d]);
#pragma unroll
      for (int e = 0; e < 3; ++e) enc[e][d] = fdot2(hh[e], wd, enc[e][d]);
    }
  }
  // per-entity epilogue, strictly in entity order (fp32, verbatim R20)
#pragma unroll
  for (int e = 0; e < 3; ++e) {
    float s = 0.f;
#pragma unroll
    for (int d = 0; d < 16; ++d) {
      enc[e][d] = fmaxf(enc[e][d], 0.f);
      s = fmaf(self_out[d], enc[e][d], s);
    }
    s *= 0.25f;
    float mn = fmaxf(m, s);
    float alpha = __expf(m - mn), w = __expf(s - mn);
    l = fmaf(l, alpha, w);
#pragma unroll
    for (int d = 0; d < 16; ++d) acc[d] = fmaf(acc[d], alpha, w * enc[e][d]);
    m = mn;
  }
}

// ---- one batch of 4 "food" entities (inputs pre-loaded, weights LDS) -----
__device__ __forceinline__ void go_batch4(const float4 q0i, const float4 q1i,
                                          const Weights& W,
                                          const uint32_t* __restrict__ swl,
                                          const float (&self_out)[16],
                                          float (&acc)[16], float& m, float& l) {
  h2 ah[4];
  ah[0] = pkrtz(q0i.x, q0i.y);
  ah[1] = pkrtz(q0i.z, q0i.w);
  ah[2] = pkrtz(q1i.x, q1i.y);
  ah[3] = pkrtz(q1i.z, q1i.w);
  float enc[4][16];
#pragma unroll
  for (int d = 0; d < 16; ++d) {
    float b2 = W.go_b2[d];
#pragma unroll
    for (int e = 0; e < 4; ++e) enc[e][d] = b2;
  }
#pragma unroll 2
  for (int jp = 0; jp < 16; ++jp) {
    const uint2 g1 = *reinterpret_cast<const uint2*>(&swl[L_GO_L1 + jp*2]);
    const float2 bb = *reinterpret_cast<const float2*>(
        &reinterpret_cast<const float*>(swl)[L_GO_B1 + jp*2]);
    const uint4 q0 = *reinterpret_cast<const uint4*>(&swl[L_GO_L2 + jp*16 + 0]);
    const uint4 q1 = *reinterpret_cast<const uint4*>(&swl[L_GO_L2 + jp*16 + 4]);
    const uint4 q2 = *reinterpret_cast<const uint4*>(&swl[L_GO_L2 + jp*16 + 8]);
    const uint4 q3 = *reinterpret_cast<const uint4*>(&swl[L_GO_L2 + jp*16 + 12]);
    const h2 w0 = asH2(g1.x), w1 = asH2(g1.y);
    h2 hh[4];
#pragma unroll
    for (int e = 0; e < 4; ++e) {
      float h0 = fmaxf(fdot2(ah[e], w0, bb.x), 0.f);
      float h1 = fmaxf(fdot2(ah[e], w1, bb.y), 0.f);
      hh[e] = pkrtz(h0, h1);
    }
    const uint32_t l2[16] = {q0.x, q0.y, q0.z, q0.w, q1.x, q1.y, q1.z, q1.w,
                             q2.x, q2.y, q2.z, q2.w, q3.x, q3.y, q3.z, q3.w};
#pragma unroll
    for (int d = 0; d < 16; ++d) {
      const h2 wd = asH2(l2[d]);
#pragma unroll
      for (int e = 0; e < 4; ++e) enc[e][d] = fdot2(hh[e], wd, enc[e][d]);
    }
  }
  // per-entity epilogue, strictly in entity order (fp32, verbatim R20)
#pragma unroll
  for (int e = 0; e < 4; ++e) {
    float s = 0.f;
#pragma unroll
    for (int d = 0; d < 16; ++d) {
      enc[e][d] = fmaxf(enc[e][d], 0.f);
      s = fmaf(self_out[d], enc[e][d], s);
    }
    s *= 0.25f;
    float mn = fmaxf(m, s);
    float alpha = __expf(m - mn), w = __expf(s - mn);
    l = fmaf(l, alpha, w);
#pragma unroll
    for (int d = 0; d < 16; ++d) acc[d] = fmaf(acc[d], alpha, w * enc[e][d]);
    m = mn;
  }
}

__global__ __launch_bounds__(256, 2)
void actor_fwd(const float* __restrict__ s_input, Weights W,
               const uint32_t* __restrict__ wsu,
               float* __restrict__ out, int bsz) {
  const int lane    = threadIdx.x & 63;
  const int wv      = threadIdx.x >> 6;      // 0..3
  const int pairIdx = wv >> 1;               // 0..1  (64-row group)
  const int role    = wv & 1;                // 0: other+head, 1: food
  int row = blockIdx.x * 128 + pairIdx * 64 + lane;
  row = min(row, bsz - 1);
  const float* __restrict__ srow = s_input + (size_t)row * 96;

  __shared__ __align__(16) uint32_t swl[L_TOTAL];  // weight pool (7.9KB)
  __shared__ float fpool[2][64][17];               // +1 pad: conflict-free

  // ---- one-time weight staging: wsu (global, packed) -> LDS -------------
  {
    const int t = threadIdx.x;
    if (t < 64) {
      int jp = t >> 2, c = t & 3;
      swl[L_OA_L1 + t] = wsu[P_OA_W1 + (c & 2) * 16 + 2 * jp + (c & 1)];
    }
    swl[L_OA_L2 + t] = wsu[P_OA_W2 + t];           // 256 contiguous
    swl[L_GO_L2 + t] = wsu[P_GO_W2 + t];           // 256 contiguous
    if (t < 32) {
      swl[L_GO_L1 + t] = wsu[P_GO_W1 + t];
      reinterpret_cast<float*>(swl)[L_OA_B1 + t] = W.oa_b1[t];
      reinterpret_cast<float*>(swl)[L_GO_B1 + t] = W.go_b1[t];
    }
    // head weights: a_W1(768) a_W2(512) a_W3(32) contiguous in wsu
#pragma unroll 1
    for (int i = t; i < 1312; i += 256)
      swl[H_A_W1 + i] = wsu[P_A_W1 + i];
  }

  // ---- prefetch: self inputs (both) + batch-0 inputs (per role) ---------
  float4 pself = ld4(srow);                  // cols 0..3, 16B-aligned
  float2 pre01[3], pre23[3];                 // oa pipeline regs (role 0)
  float4 preq0, preq1;                       // go pipeline regs (role 1)
  if (role == 0) {
#pragma unroll
    for (int e = 0; e < 3; ++e) {
      pre01[e] = ld2(srow + 4  + 2*e);
      pre23[e] = ld2(srow + 34 + 2*e);
    }
  } else {
    preq0 = ld4(srow + 64);                  // cols 64..67, aligned
    preq1 = ld4(srow + 68);
  }

  __syncthreads();                           // staging visible to all waves

  // ---------------- self encoder (both roles): 4 -> 32 -> 16, relu --------
  // stays on SMEM (R20): scalar-pipe loads, amortized, nothing to gain in LDS
  float self_out[16];
  {
    h2 a01 = pkrtz(pself.x, pself.y);
    h2 a23 = pkrtz(pself.z, pself.w);
#pragma unroll
    for (int d = 0; d < 16; ++d) self_out[d] = W.en_b2[d];
#pragma unroll
    for (int jp = 0; jp < 16; ++jp) {
      const int j0 = 2*jp, j1 = 2*jp + 1;
      float h0 = fmaxf(fdot2(a01, asH2(wsu[P_EN_W1 + j0]),
                     fdot2(a23, asH2(wsu[P_EN_W1 + 32 + j0]), W.en_b1[j0])), 0.f);
      float h1 = fmaxf(fdot2(a01, asH2(wsu[P_EN_W1 + j1]),
                     fdot2(a23, asH2(wsu[P_EN_W1 + 32 + j1]), W.en_b1[j1])), 0.f);
      h2 hh = pkrtz(h0, h1);
#pragma unroll
      for (int d = 0; d < 16; ++d)
        self_out[d] = fdot2(hh, asH2(wsu[P_EN_W2 + jp*16 + d]), self_out[d]);
    }
#pragma unroll
    for (int d = 0; d < 16; ++d) self_out[d] = fmaxf(self_out[d], 0.f);
  }

  float other_pool[16];

  if (role == 0) {
    // ------- other agents: 15 entities = 5 passes of 3, prefetched -------
    float m = -3.0e38f, l = 0.f, acc[16];
#pragma unroll
    for (int d = 0; d < 16; ++d) acc[d] = 0.f;
#pragma unroll 1
    for (int k0 = 0; k0 < 15; k0 += 3) {
      float2 c01[3], c23[3];
#pragma unroll
      for (int e = 0; e < 3; ++e) { c01[e] = pre01[e]; c23[e] = pre23[e]; }
      if (k0 + 3 < 15) {
#pragma unroll
        for (int e = 0; e < 3; ++e) {
          pre01[e] = ld2(srow + 4  + 2*(k0 + 3 + e));
          pre23[e] = ld2(srow + 34 + 2*(k0 + 3 + e));
        }
      }
      oa_batch3(c01, c23, W, swl, self_out, acc, m, l);
    }

    float inv = 1.f / l;
    float mu = 0.f;
#pragma unroll
    for (int d = 0; d < 16; ++d) { acc[d] *= inv; mu += acc[d]; }
    mu *= (1.f / 16.f);
    float var = 0.f;
#pragma unroll
    for (int d = 0; d < 16; ++d) { float x = acc[d] - mu; var = fmaf(x, x, var); }
    var *= (1.f / 16.f);
    float rstd = rsqrtf(var + LN_EPS);
#pragma unroll
    for (int d = 0; d < 16; ++d)
      other_pool[d] = fmaxf(fmaf((acc[d] - mu) * rstd, W.oa_g[d], W.oa_b[d]), 0.f);
  } else {
    // ------- food: 16 entities = 4 passes of 4 (float4), prefetched ------
    float m = -3.0e38f, l = 0.f, acc[16];
#pragma unroll
    for (int d = 0; d < 16; ++d) acc[d] = 0.f;
#pragma unroll 1
    for (int k0 = 0; k0 < 16; k0 += 4) {
      float4 c0 = preq0, c1 = preq1;
      if (k0 + 4 < 16) {
        preq0 = ld4(srow + 64 + 2*(k0 + 4));
        preq1 = ld4(srow + 68 + 2*(k0 + 4));
      }
      go_batch4(c0, c1, W, swl, self_out, acc, m, l);
    }

    float inv = 1.f / l;
    float mu = 0.f;
#pragma unroll
    for (int d = 0; d < 16; ++d) { acc[d] *= inv; mu += acc[d]; }
    mu *= (1.f / 16.f);
    float var = 0.f;
#pragma unroll
    for (int d = 0; d < 16; ++d) { float x = acc[d] - mu; var = fmaf(x, x, var); }
    var *= (1.f / 16.f);
    float rstd = rsqrtf(var + LN_EPS);
#pragma unroll
    for (int d = 0; d < 16; ++d) {
      float fp = fmaxf(fmaf((acc[d] - mu) * rstd, W.go_g[d], W.go_b[d]), 0.f);
      fpool[pairIdx][lane][d] = fp;
    }
  }

  __syncthreads();
  if (role != 0) return;

  // ------- action head (role 0): 48 -> 32 -> 32 -> 2, weights via LDS ----
  float food_pool[16];
#pragma unroll
  for (int d = 0; d < 16; ++d) food_pool[d] = fpool[pairIdx][lane][d];

  h2 mh[24];
#pragma unroll
  for (int c = 0; c < 8; ++c) mh[c]      = pkrtz(self_out[2*c],  self_out[2*c+1]);
#pragma unroll
  for (int c = 0; c < 8; ++c) mh[8 + c]  = pkrtz(food_pool[2*c], food_pool[2*c+1]);
#pragma unroll
  for (int c = 0; c < 8; ++c) mh[16 + c] = pkrtz(other_pool[2*c], other_pool[2*c+1]);

  float h1v[32];
#pragma unroll
  for (int j = 0; j < 32; ++j) h1v[j] = W.a_b1[j];
#pragma unroll
  for (int cp = 0; cp < 24; ++cp) {      // full unroll: mh index must be static
    h2 v = mh[cp];
#pragma unroll
    for (int g = 0; g < 8; ++g) {        // uint4 consumed immediately
      const uint4 q = *reinterpret_cast<const uint4*>(&swl[H_A_W1 + cp*32 + g*4]);
      h1v[4*g+0] = fdot2(v, asH2(q.x), h1v[4*g+0]);
      h1v[4*g+1] = fdot2(v, asH2(q.y), h1v[4*g+1]);
      h1v[4*g+2] = fdot2(v, asH2(q.z), h1v[4*g+2]);
      h1v[4*g+3] = fdot2(v, asH2(q.w), h1v[4*g+3]);
    }
  }
#pragma unroll
  for (int j = 0; j < 32; ++j) h1v[j] = fmaxf(h1v[j], 0.01f * h1v[j]);  // leaky

  h2 hh1[16];
#pragma unroll
  for (int c = 0; c < 16; ++c) hh1[c] = pkrtz(h1v[2*c], h1v[2*c+1]);

  float h2v[32];
#pragma unroll
  for (int j = 0; j < 32; ++j) h2v[j] = W.a_b2[j];
#pragma unroll
  for (int cp = 0; cp < 16; ++cp) {      // full unroll: hh1 index static
    h2 v = hh1[cp];
#pragma unroll
    for (int g = 0; g < 8; ++g) {
      const uint4 q = *reinterpret_cast<const uint4*>(&swl[H_A_W2 + cp*32 + g*4]);
      h2v[4*g+0] = fdot2(v, asH2(q.x), h2v[4*g+0]);
      h2v[4*g+1] = fdot2(v, asH2(q.y), h2v[4*g+1]);
      h2v[4*g+2] = fdot2(v, asH2(q.z), h2v[4*g+2]);
      h2v[4*g+3] = fdot2(v, asH2(q.w), h2v[4*g+3]);
    }
  }
#pragma unroll
  for (int j = 0; j < 32; ++j) h2v[j] = fmaxf(h2v[j], 0.01f * h2v[j]);

  h2 hh2[16];
#pragma unroll
  for (int c = 0; c < 16; ++c) hh2[c] = pkrtz(h2v[2*c], h2v[2*c+1]);

  float o0 = W.a_b3[0], o1 = W.a_b3[1];
#pragma unroll
  for (int cp = 0; cp < 16; ++cp) {
    const uint2 q = *reinterpret_cast<const uint2*>(&swl[H_A_W3 + cp*2]);
    o0 = fdot2(hh2[cp], asH2(q.x), o0);
    o1 = fdot2(hh2[cp], asH2(q.y), o1);
  }
  o0 = tanhf(o0);
  o1 = tanhf(o1);

  reinterpret_cast<float2*>(out)[row] = make_float2(o0, o1);
}

extern "C" void kernel_launch(void* const* d_in, const int* in_sizes, int n_in,
                              void* d_out, int out_size, void* d_ws, size_t ws_size,
                              hipStream_t stream) {
  const float* s_input = (const float*)d_in[0];
  Weights W;
  W.en_W1 = (const float*)d_in[1];  W.en_b1 = (const float*)d_in[2];
  W.en_W2 = (const float*)d_in[3];  W.en_b2 = (const float*)d_in[4];
  W.oa_W1 = (const float*)d_in[5];  W.oa_b1 = (const float*)d_in[6];
  W.oa_W2 = (const float*)d_in[7];  W.oa_b2 = (const float*)d_in[8];
  W.go_W1 = (const float*)d_in[9];  W.go_b1 = (const float*)d_in[10];
  W.go_W2 = (const float*)d_in[11]; W.go_b2 = (const float*)d_in[12];
  W.oa_g  = (const float*)d_in[13]; W.oa_b  = (const float*)d_in[14];
  W.go_g  = (const float*)d_in[15]; W.go_b  = (const float*)d_in[16];
  W.a_W1  = (const float*)d_in[17]; W.a_b1  = (const float*)d_in[18];
  W.a_W2  = (const float*)d_in[19]; W.a_b2  = (const float*)d_in[20];
  W.a_W3  = (const float*)d_in[21]; W.a_b3  = (const float*)d_in[22];

  uint32_t* wsu = (uint32_t*)d_ws;   // needs 8960 bytes
  prep_weights<<<1, 256, 0, stream>>>(W, wsu);

  const int bsz = in_sizes[0] / 96;          // 262144
  const int blocks = (bsz + 127) / 128;      // 128 rows/block: 2 groups x 2 roles
  actor_fwd<<<blocks, 256, 0, stream>>>(s_input, W, wsu, (float*)d_out, bsz);
}

// Round 14
// 296.122 us; speedup vs baseline: 1.0159x; 1.0046x over previous
//
#include <hip/hip_runtime.h>
#include <stdint.h>

// Actor_attf_single — MI355X (gfx950)
// R23 = R20 verbatim (session best: 160us kernel). Final structure.
// Session ledger (kernel time):
//   R8  329 fp32 2-batch        R13 291 fp32 3/4-batch
//   R16 230 fp16 dot2 (halved MAC instruction count; busy 552K->328K)
//   R17 199 + role-split TLP    R19 173.5 + input prefetch (stall -72K)
//   R20 160 + oa/go pass weights via LDS (ds_read counted lgkmcnt(N)
//       pipelines; SMEM lgkmcnt(0) drains eliminated in the hot loops)
//   R21 166 all-LDS (self move regressed)  R22 164 head-LDS (no gain)
// Dead ends (3 strikes): __launch_bounds__ min-waves>2 => allocator spills
// destructively (R11/R14/R18). This kernel lives at VGPR 84, 4 waves/SIMD.
// Plateau accounting: busy ~301K cyc/SIMD (VALU-issue floor at dot2
// budget) + stall ~83K (latency floor TLP can't hide at 4 waves/SIMD).
// absmax 0.00390625 — bit-identical to the fp32 reference path throughout.

#define LN_EPS 1e-5f

typedef _Float16 h2 __attribute__((ext_vector_type(2)));

struct Weights {
  const float* __restrict__ en_W1; const float* __restrict__ en_b1;
  const float* __restrict__ en_W2; const float* __restrict__ en_b2;
  const float* __restrict__ oa_W1; const float* __restrict__ oa_b1;
  const float* __restrict__ oa_W2; const float* __restrict__ oa_b2;
  const float* __restrict__ go_W1; const float* __restrict__ go_b1;
  const float* __restrict__ go_W2; const float* __restrict__ go_b2;
  const float* __restrict__ oa_g;  const float* __restrict__ oa_b;
  const float* __restrict__ go_g;  const float* __restrict__ go_b;
  const float* __restrict__ a_W1;  const float* __restrict__ a_b1;
  const float* __restrict__ a_W2;  const float* __restrict__ a_b2;
  const float* __restrict__ a_W3;  const float* __restrict__ a_b3;
};

// workspace layout (uint32 = packed half2 units)
constexpr int P_EN_W1 = 0;     //  64
constexpr int P_EN_W2 = 64;    // 256
constexpr int P_OA_W1 = 320;   //  64
constexpr int P_OA_W2 = 384;   // 256
constexpr int P_GO_W1 = 640;   //  32
constexpr int P_GO_W2 = 672;   // 256
constexpr int P_A_W1  = 928;   // 768
constexpr int P_A_W2  = 1696;  // 512
constexpr int P_A_W3  = 2208;  //  32
// total 2240 u32 = 8960 bytes

// LDS weight-pool offsets (u32 units; uint4 arrays 16B-aligned)
constexpr int L_OA_L1 = 0;     //  64: [jp*4+c] = {wA0,wA1,wB0,wB1}
constexpr int L_OA_L2 = 64;    // 256: [jp*16+d]
constexpr int L_GO_L2 = 320;   // 256: [jp*16+d]
constexpr int L_GO_L1 = 576;   //  32: [jp*2+{0,1}]   (8B-aligned)
constexpr int L_OA_B1 = 608;   //  32 floats: [jp*2+{0,1}]
constexpr int L_GO_B1 = 640;   //  32 floats
constexpr int L_TOTAL = 672;   // 2688 bytes

__device__ __forceinline__ float2 ld2(const float* __restrict__ p) {
  return *reinterpret_cast<const float2*>(p);
}
__device__ __forceinline__ float4 ld4(const float* __restrict__ p) {
  return *reinterpret_cast<const float4*>(p);
}
__device__ __forceinline__ uint32_t pack_rne(float a, float b) {
  h2 v; v.x = (_Float16)a; v.y = (_Float16)b;
  return __builtin_bit_cast(uint32_t, v);
}
__device__ __forceinline__ h2 asH2(uint32_t u) { return __builtin_bit_cast(h2, u); }
__device__ __forceinline__ float fdot2(h2 a, h2 b, float c) {
  return __builtin_amdgcn_fdot2(a, b, c, false);
}
__device__ __forceinline__ h2 pkrtz(float a, float b) {
  return __builtin_bit_cast(h2, __builtin_amdgcn_cvt_pkrtz(a, b));
}

// ---- prep: fp32 weights -> packed half2 in workspace ---------------------
__global__ void prep_weights(Weights W, uint32_t* __restrict__ ws) {
  const int t = threadIdx.x;
  if (t < 32) {
    ws[P_EN_W1 + t]      = pack_rne(W.en_W1[t],      W.en_W1[32 + t]);
    ws[P_EN_W1 + 32 + t] = pack_rne(W.en_W1[64 + t], W.en_W1[96 + t]);
    ws[P_OA_W1 + t]      = pack_rne(W.oa_W1[t],      W.oa_W1[32 + t]);
    ws[P_OA_W1 + 32 + t] = pack_rne(W.oa_W1[64 + t], W.oa_W1[96 + t]);
    ws[P_GO_W1 + t]      = pack_rne(W.go_W1[t],      W.go_W1[32 + t]);
  }
  {
    int jp = t >> 4, d = t & 15;
    ws[P_EN_W2 + t] = pack_rne(W.en_W2[(2*jp)*16 + d], W.en_W2[(2*jp+1)*16 + d]);
    ws[P_OA_W2 + t] = pack_rne(W.oa_W2[(2*jp)*16 + d], W.oa_W2[(2*jp+1)*16 + d]);
    ws[P_GO_W2 + t] = pack_rne(W.go_W2[(2*jp)*16 + d], W.go_W2[(2*jp+1)*16 + d]);
  }
  for (int i = t; i < 768; i += 256) {
    int cp = i >> 5, j = i & 31;
    ws[P_A_W1 + i] = pack_rne(W.a_W1[(2*cp)*32 + j], W.a_W1[(2*cp+1)*32 + j]);
  }
  for (int i = t; i < 512; i += 256) {
    int cp = i >> 5, j = i & 31;
    ws[P_A_W2 + i] = pack_rne(W.a_W2[(2*cp)*32 + j], W.a_W2[(2*cp+1)*32 + j]);
  }
  if (t < 32) {
    int cp = t >> 1, o = t & 1;
    ws[P_A_W3 + t] = pack_rne(W.a_W3[(2*cp)*2 + o], W.a_W3[(2*cp+1)*2 + o]);
  }
}

// ---- one batch of 3 "other" entities (inputs pre-loaded, weights LDS) ----
__device__ __forceinline__ void oa_batch3(const float2 (&i01)[3],
                                          const float2 (&i23)[3],
                                          const Weights& W,
                                          const uint32_t* __restrict__ swl,
                                          const float (&self_out)[16],
                                          float (&acc)[16], float& m, float& l) {
  h2 a01[3], a23[3];
#pragma unroll
  for (int e = 0; e < 3; ++e) {
    a01[e] = pkrtz(i01[e].x, i01[e].y);
    a23[e] = pkrtz(i23[e].x, i23[e].y);
  }
  float enc[3][16];
#pragma unroll
  for (int d = 0; d < 16; ++d) {
    float b2 = W.oa_b2[d];
#pragma unroll
    for (int e = 0; e < 3; ++e) enc[e][d] = b2;
  }
#pragma unroll 2
  for (int jp = 0; jp < 16; ++jp) {
    const uint4 l1 = *reinterpret_cast<const uint4*>(&swl[L_OA_L1 + jp*4]);
    const float2 bb = *reinterpret_cast<const float2*>(
        &reinterpret_cast<const float*>(swl)[L_OA_B1 + jp*2]);
    const uint4 q0 = *reinterpret_cast<const uint4*>(&swl[L_OA_L2 + jp*16 + 0]);
    const uint4 q1 = *reinterpret_cast<const uint4*>(&swl[L_OA_L2 + jp*16 + 4]);
    const uint4 q2 = *reinterpret_cast<const uint4*>(&swl[L_OA_L2 + jp*16 + 8]);
    const uint4 q3 = *reinterpret_cast<const uint4*>(&swl[L_OA_L2 + jp*16 + 12]);
    const h2 wA0 = asH2(l1.x), wA1 = asH2(l1.y);
    const h2 wB0 = asH2(l1.z), wB1 = asH2(l1.w);
    h2 hh[3];
#pragma unroll
    for (int e = 0; e < 3; ++e) {
      float h0 = fmaxf(fdot2(a01[e], wA0, fdot2(a23[e], wB0, bb.x)), 0.f);
      float h1 = fmaxf(fdot2(a01[e], wA1, fdot2(a23[e], wB1, bb.y)), 0.f);
      hh[e] = pkrtz(h0, h1);
    }
    const uint32_t l2[16] = {q0.x, q0.y, q0.z, q0.w, q1.x, q1.y, q1.z, q1.w,
                             q2.x, q2.y, q2.z, q2.w, q3.x, q3.y, q3.z, q3.w};
#pragma unroll
    for (int d = 0; d < 16; ++d) {
      const h2 wd = asH2(l2[d]);
#pragma unroll
      for (int e = 0; e < 3; ++e) enc[e][d] = fdot2(hh[e], wd, enc[e][d]);
    }
  }
  // per-entity epilogue, strictly in entity order
#pragma unroll
  for (int e = 0; e < 3; ++e) {
    float s = 0.f;
#pragma unroll
    for (int d = 0; d < 16; ++d) {
      enc[e][d] = fmaxf(enc[e][d], 0.f);
      s = fmaf(self_out[d], enc[e][d], s);
    }
    s *= 0.25f;
    float mn = fmaxf(m, s);
    float alpha = __expf(m - mn), w = __expf(s - mn);
    l = fmaf(l, alpha, w);
#pragma unroll
    for (int d = 0; d < 16; ++d) acc[d] = fmaf(acc[d], alpha, w * enc[e][d]);
    m = mn;
  }
}

// ---- one batch of 4 "food" entities (inputs pre-loaded, weights LDS) -----
__device__ __forceinline__ void go_batch4(const float4 q0i, const float4 q1i,
                                          const Weights& W,
                                          const uint32_t* __restrict__ swl,
                                          const float (&self_out)[16],
                                          float (&acc)[16], float& m, float& l) {
  h2 ah[4];
  ah[0] = pkrtz(q0i.x, q0i.y);
  ah[1] = pkrtz(q0i.z, q0i.w);
  ah[2] = pkrtz(q1i.x, q1i.y);
  ah[3] = pkrtz(q1i.z, q1i.w);
  float enc[4][16];
#pragma unroll
  for (int d = 0; d < 16; ++d) {
    float b2 = W.go_b2[d];
#pragma unroll
    for (int e = 0; e < 4; ++e) enc[e][d] = b2;
  }
#pragma unroll 2
  for (int jp = 0; jp < 16; ++jp) {
    const uint2 g1 = *reinterpret_cast<const uint2*>(&swl[L_GO_L1 + jp*2]);
    const float2 bb = *reinterpret_cast<const float2*>(
        &reinterpret_cast<const float*>(swl)[L_GO_B1 + jp*2]);
    const uint4 q0 = *reinterpret_cast<const uint4*>(&swl[L_GO_L2 + jp*16 + 0]);
    const uint4 q1 = *reinterpret_cast<const uint4*>(&swl[L_GO_L2 + jp*16 + 4]);
    const uint4 q2 = *reinterpret_cast<const uint4*>(&swl[L_GO_L2 + jp*16 + 8]);
    const uint4 q3 = *reinterpret_cast<const uint4*>(&swl[L_GO_L2 + jp*16 + 12]);
    const h2 w0 = asH2(g1.x), w1 = asH2(g1.y);
    h2 hh[4];
#pragma unroll
    for (int e = 0; e < 4; ++e) {
      float h0 = fmaxf(fdot2(ah[e], w0, bb.x), 0.f);
      float h1 = fmaxf(fdot2(ah[e], w1, bb.y), 0.f);
      hh[e] = pkrtz(h0, h1);
    }
    const uint32_t l2[16] = {q0.x, q0.y, q0.z, q0.w, q1.x, q1.y, q1.z, q1.w,
                             q2.x, q2.y, q2.z, q2.w, q3.x, q3.y, q3.z, q3.w};
#pragma unroll
    for (int d = 0; d < 16; ++d) {
      const h2 wd = asH2(l2[d]);
#pragma unroll
      for (int e = 0; e < 4; ++e) enc[e][d] = fdot2(hh[e], wd, enc[e][d]);
    }
  }
  // per-entity epilogue, strictly in entity order
#pragma unroll
  for (int e = 0; e < 4; ++e) {
    float s = 0.f;
#pragma unroll
    for (int d = 0; d < 16; ++d) {
      enc[e][d] = fmaxf(enc[e][d], 0.f);
      s = fmaf(self_out[d], enc[e][d], s);
    }
    s *= 0.25f;
    float mn = fmaxf(m, s);
    float alpha = __expf(m - mn), w = __expf(s - mn);
    l = fmaf(l, alpha, w);
#pragma unroll
    for (int d = 0; d < 16; ++d) acc[d] = fmaf(acc[d], alpha, w * enc[e][d]);
    m = mn;
  }
}

__global__ __launch_bounds__(256, 2)
void actor_fwd(const float* __restrict__ s_input, Weights W,
               const uint32_t* __restrict__ wsu,
               float* __restrict__ out, int bsz) {
  const int lane    = threadIdx.x & 63;
  const int wv      = threadIdx.x >> 6;      // 0..3
  const int pairIdx = wv >> 1;               // 0..1  (64-row group)
  const int role    = wv & 1;                // 0: other+head, 1: food
  int row = blockIdx.x * 128 + pairIdx * 64 + lane;
  row = min(row, bsz - 1);
  const float* __restrict__ srow = s_input + (size_t)row * 96;

  __shared__ __align__(16) uint32_t swl[L_TOTAL];  // weight pool (2.7KB)
  __shared__ float fpool[2][64][17];               // +1 pad: conflict-free

  // ---- one-time weight staging: wsu (global, packed) -> LDS -------------
  {
    const int t = threadIdx.x;
    if (t < 64) {
      int jp = t >> 2, c = t & 3;
      swl[L_OA_L1 + t] = wsu[P_OA_W1 + (c & 2) * 16 + 2 * jp + (c & 1)];
    }
    swl[L_OA_L2 + t] = wsu[P_OA_W2 + t];           // 256 contiguous
    swl[L_GO_L2 + t] = wsu[P_GO_W2 + t];           // 256 contiguous
    if (t < 32) {
      swl[L_GO_L1 + t] = wsu[P_GO_W1 + t];
      reinterpret_cast<float*>(swl)[L_OA_B1 + t] = W.oa_b1[t];
      reinterpret_cast<float*>(swl)[L_GO_B1 + t] = W.go_b1[t];
    }
  }

  // ---- prefetch: self inputs (both) + batch-0 inputs (per role) ---------
  float4 pself = ld4(srow);                  // cols 0..3, 16B-aligned
  float2 pre01[3], pre23[3];                 // oa pipeline regs (role 0)
  float4 preq0, preq1;                       // go pipeline regs (role 1)
  if (role == 0) {
#pragma unroll
    for (int e = 0; e < 3; ++e) {
      pre01[e] = ld2(srow + 4  + 2*e);
      pre23[e] = ld2(srow + 34 + 2*e);
    }
  } else {
    preq0 = ld4(srow + 64);                  // cols 64..67, aligned
    preq1 = ld4(srow + 68);
  }

  __syncthreads();                           // staging visible to all waves

  // ---------------- self encoder (both roles): 4 -> 32 -> 16, relu --------
  float self_out[16];
  {
    h2 a01 = pkrtz(pself.x, pself.y);
    h2 a23 = pkrtz(pself.z, pself.w);
#pragma unroll
    for (int d = 0; d < 16; ++d) self_out[d] = W.en_b2[d];
#pragma unroll
    for (int jp = 0; jp < 16; ++jp) {
      const int j0 = 2*jp, j1 = 2*jp + 1;
      float h0 = fmaxf(fdot2(a01, asH2(wsu[P_EN_W1 + j0]),
                     fdot2(a23, asH2(wsu[P_EN_W1 + 32 + j0]), W.en_b1[j0])), 0.f);
      float h1 = fmaxf(fdot2(a01, asH2(wsu[P_EN_W1 + j1]),
                     fdot2(a23, asH2(wsu[P_EN_W1 + 32 + j1]), W.en_b1[j1])), 0.f);
      h2 hh = pkrtz(h0, h1);
#pragma unroll
      for (int d = 0; d < 16; ++d)
        self_out[d] = fdot2(hh, asH2(wsu[P_EN_W2 + jp*16 + d]), self_out[d]);
    }
#pragma unroll
    for (int d = 0; d < 16; ++d) self_out[d] = fmaxf(self_out[d], 0.f);
  }

  float other_pool[16];

  if (role == 0) {
    // ------- other agents: 15 entities = 5 passes of 3, prefetched -------
    float m = -3.0e38f, l = 0.f, acc[16];
#pragma unroll
    for (int d = 0; d < 16; ++d) acc[d] = 0.f;
#pragma unroll 1
    for (int k0 = 0; k0 < 15; k0 += 3) {
      float2 c01[3], c23[3];
#pragma unroll
      for (int e = 0; e < 3; ++e) { c01[e] = pre01[e]; c23[e] = pre23[e]; }
      if (k0 + 3 < 15) {
#pragma unroll
        for (int e = 0; e < 3; ++e) {
          pre01[e] = ld2(srow + 4  + 2*(k0 + 3 + e));
          pre23[e] = ld2(srow + 34 + 2*(k0 + 3 + e));
        }
      }
      oa_batch3(c01, c23, W, swl, self_out, acc, m, l);
    }

    float inv = 1.f / l;
    float mu = 0.f;
#pragma unroll
    for (int d = 0; d < 16; ++d) { acc[d] *= inv; mu += acc[d]; }
    mu *= (1.f / 16.f);
    float var = 0.f;
#pragma unroll
    for (int d = 0; d < 16; ++d) { float x = acc[d] - mu; var = fmaf(x, x, var); }
    var *= (1.f / 16.f);
    float rstd = rsqrtf(var + LN_EPS);
#pragma unroll
    for (int d = 0; d < 16; ++d)
      other_pool[d] = fmaxf(fmaf((acc[d] - mu) * rstd, W.oa_g[d], W.oa_b[d]), 0.f);
  } else {
    // ------- food: 16 entities = 4 passes of 4 (float4), prefetched ------
    float m = -3.0e38f, l = 0.f, acc[16];
#pragma unroll
    for (int d = 0; d < 16; ++d) acc[d] = 0.f;
#pragma unroll 1
    for (int k0 = 0; k0 < 16; k0 += 4) {
      float4 c0 = preq0, c1 = preq1;
      if (k0 + 4 < 16) {
        preq0 = ld4(srow + 64 + 2*(k0 + 4));
        preq1 = ld4(srow + 68 + 2*(k0 + 4));
      }
      go_batch4(c0, c1, W, swl, self_out, acc, m, l);
    }

    float inv = 1.f / l;
    float mu = 0.f;
#pragma unroll
    for (int d = 0; d < 16; ++d) { acc[d] *= inv; mu += acc[d]; }
    mu *= (1.f / 16.f);
    float var = 0.f;
#pragma unroll
    for (int d = 0; d < 16; ++d) { float x = acc[d] - mu; var = fmaf(x, x, var); }
    var *= (1.f / 16.f);
    float rstd = rsqrtf(var + LN_EPS);
#pragma unroll
    for (int d = 0; d < 16; ++d) {
      float fp = fmaxf(fmaf((acc[d] - mu) * rstd, W.go_g[d], W.go_b[d]), 0.f);
      fpool[pairIdx][lane][d] = fp;
    }
  }

  __syncthreads();
  if (role != 0) return;

  // ------- action head (role 0): 48 -> 32 -> 32 -> 2, via dot2 -----------
  float food_pool[16];
#pragma unroll
  for (int d = 0; d < 16; ++d) food_pool[d] = fpool[pairIdx][lane][d];

  h2 mh[24];
#pragma unroll
  for (int c = 0; c < 8; ++c) mh[c]      = pkrtz(self_out[2*c],  self_out[2*c+1]);
#pragma unroll
  for (int c = 0; c < 8; ++c) mh[8 + c]  = pkrtz(food_pool[2*c], food_pool[2*c+1]);
#pragma unroll
  for (int c = 0; c < 8; ++c) mh[16 + c] = pkrtz(other_pool[2*c], other_pool[2*c+1]);

  float h1v[32];
#pragma unroll
  for (int j = 0; j < 32; ++j) h1v[j] = W.a_b1[j];
#pragma unroll
  for (int cp = 0; cp < 24; ++cp) {
    h2 v = mh[cp];
#pragma unroll
    for (int j = 0; j < 32; ++j)
      h1v[j] = fdot2(v, asH2(wsu[P_A_W1 + cp*32 + j]), h1v[j]);
  }
#pragma unroll
  for (int j = 0; j < 32; ++j) h1v[j] = fmaxf(h1v[j], 0.01f * h1v[j]);  // leaky

  h2 hh1[16];
#pragma unroll
  for (int c = 0; c < 16; ++c) hh1[c] = pkrtz(h1v[2*c], h1v[2*c+1]);

  float h2v[32];
#pragma unroll
  for (int j = 0; j < 32; ++j) h2v[j] = W.a_b2[j];
#pragma unroll
  for (int cp = 0; cp < 16; ++cp) {
    h2 v = hh1[cp];
#pragma unroll
    for (int j = 0; j < 32; ++j)
      h2v[j] = fdot2(v, asH2(wsu[P_A_W2 + cp*32 + j]), h2v[j]);
  }
#pragma unroll
  for (int j = 0; j < 32; ++j) h2v[j] = fmaxf(h2v[j], 0.01f * h2v[j]);

  h2 hh2[16];
#pragma unroll
  for (int c = 0; c < 16; ++c) hh2[c] = pkrtz(h2v[2*c], h2v[2*c+1]);

  float o0 = W.a_b3[0], o1 = W.a_b3[1];
#pragma unroll
  for (int cp = 0; cp < 16; ++cp) {
    o0 = fdot2(hh2[cp], asH2(wsu[P_A_W3 + cp*2 + 0]), o0);
    o1 = fdot2(hh2[cp], asH2(wsu[P_A_W3 + cp*2 + 1]), o1);
  }
  o0 = tanhf(o0);
  o1 = tanhf(o1);

  reinterpret_cast<float2*>(out)[row] = make_float2(o0, o1);
}

extern "C" void kernel_launch(void* const* d_in, const int* in_sizes, int n_in,
                              void* d_out, int out_size, void* d_ws, size_t ws_size,
                              hipStream_t stream) {
  const float* s_input = (const float*)d_in[0];
  Weights W;
  W.en_W1 = (const float*)d_in[1];  W.en_b1 = (const float*)d_in[2];
  W.en_W2 = (const float*)d_in[3];  W.en_b2 = (const float*)d_in[4];
  W.oa_W1 = (const float*)d_in[5];  W.oa_b1 = (const float*)d_in[6];
  W.oa_W2 = (const float*)d_in[7];  W.oa_b2 = (const float*)d_in[8];
  W.go_W1 = (const float*)d_in[9];  W.go_b1 = (const float*)d_in[10];
  W.go_W2 = (const float*)d_in[11]; W.go_b2 = (const float*)d_in[12];
  W.oa_g  = (const float*)d_in[13]; W.oa_b  = (const float*)d_in[14];
  W.go_g  = (const float*)d_in[15]; W.go_b  = (const float*)d_in[16];
  W.a_W1  = (const float*)d_in[17]; W.a_b1  = (const float*)d_in[18];
  W.a_W2  = (const float*)d_in[19]; W.a_b2  = (const float*)d_in[20];
  W.a_W3  = (const float*)d_in[21]; W.a_b3  = (const float*)d_in[22];

  uint32_t* wsu = (uint32_t*)d_ws;   // needs 8960 bytes
  prep_weights<<<1, 256, 0, stream>>>(W, wsu);

  const int bsz = in_sizes[0] / 96;          // 262144
  const int blocks = (bsz + 127) / 128;      // 128 rows/block: 2 groups x 2 roles
  actor_fwd<<<blocks, 256, 0, stream>>>(s_input, W, wsu, (float*)d_out, bsz);
}